// Round 2
// baseline (390.284 us; speedup 1.0000x reference)
//
#include <hip/hip_runtime.h>
#include <stdint.h>

#define B_  2
#define S_  2048
#define D_  2048
#define H_  16
#define HD_ 128
#define D3_ 6144

typedef unsigned short u16;
typedef __attribute__((ext_vector_type(8))) __bf16 bf16x8;
typedef __attribute__((ext_vector_type(4))) float f32x4;
typedef __attribute__((ext_vector_type(8))) u16  u16x8;
typedef __attribute__((ext_vector_type(2))) u16  u16x2;

__device__ inline u16 f2bf(float f) {
  union { float f; uint32_t u; } v; v.f = f;
  uint32_t r = v.u + 0x7FFFu + ((v.u >> 16) & 1u);
  return (u16)(r >> 16);
}
__device__ inline float bf2f(u16 u) {
  union { float f; uint32_t u; } v; v.u = ((uint32_t)u) << 16;
  return v.f;
}
__device__ inline void gload_lds16(const void* g, void* l) {
  __builtin_amdgcn_global_load_lds((const __attribute__((address_space(1))) uint32_t*)g,
                                   (__attribute__((address_space(3))) uint32_t*)l, 16, 0, 0);
}

// ---------------- fp32 -> bf16 cast ----------------
__global__ __launch_bounds__(256) void castk(const float* __restrict__ in, u16* __restrict__ out, int n) {
  int i = blockIdx.x * 256 + threadIdx.x;
  int n8 = n >> 3;
  if (i < n8) {
    f32x4 a = ((const f32x4*)in)[2*i];
    f32x4 b = ((const f32x4*)in)[2*i + 1];
    u16x8 o;
#pragma unroll
    for (int j = 0; j < 4; ++j) o[j] = f2bf(a[j]);
#pragma unroll
    for (int j = 0; j < 4; ++j) o[4+j] = f2bf(b[j]);
    ((u16x8*)out)[i] = o;
  }
}

// ---------------- B^T GEMM: C[m,n] = sum_k A[m,k]*B[n,k] ----------------
template<int BF16OUT>
__global__ __launch_bounds__(256) void gemm_bt(const u16* __restrict__ A, const u16* __restrict__ Bw,
                                               void* __restrict__ Cp, int M, int N, int K) {
  __shared__ u16 lA[128*64];
  __shared__ u16 lB[128*64];
  const int tid = threadIdx.x;
  const int w = tid >> 6, l = tid & 63;
  const int lr = l & 15, lg = l >> 4;
  const int bm = blockIdx.y, bn = blockIdx.x;
  const int wr = w >> 1, wc = w & 1;

  f32x4 acc[4][4] = {};

  int srow[4], scol[4];
#pragma unroll
  for (int i = 0; i < 4; ++i) {
    int off = (w*4 + i)*1024 + l*16;
    srow[i] = off >> 7;
    scol[i] = (off & 127) ^ ((srow[i] & 7) << 4);
  }
  const size_t rs = (size_t)K * 2;
  const char* Ab = (const char*)A + (size_t)bm * 128 * rs;
  const char* Bb = (const char*)Bw + (size_t)bn * 128 * rs;
  char* lAb = (char*)lA; char* lBb = (char*)lB;

  for (int kt = 0; kt < K; kt += 64) {
#pragma unroll
    for (int i = 0; i < 4; ++i) {
      int dst = (w*4 + i)*1024;
      gload_lds16(Ab + srow[i]*rs + kt*2 + scol[i], lAb + dst);
      gload_lds16(Bb + srow[i]*rs + kt*2 + scol[i], lBb + dst);
    }
    __syncthreads();
#pragma unroll
    for (int ks = 0; ks < 2; ++ks) {
      bf16x8 af[4], bfr[4];
#pragma unroll
      for (int mt = 0; mt < 4; ++mt) {
        int row = wr*64 + mt*16 + lr;
        af[mt] = *(const bf16x8*)(lAb + row*128 + ((ks*64 + lg*16) ^ ((row & 7) << 4)));
      }
#pragma unroll
      for (int nt = 0; nt < 4; ++nt) {
        int row = wc*64 + nt*16 + lr;
        bfr[nt] = *(const bf16x8*)(lBb + row*128 + ((ks*64 + lg*16) ^ ((row & 7) << 4)));
      }
#pragma unroll
      for (int mt = 0; mt < 4; ++mt)
#pragma unroll
        for (int nt = 0; nt < 4; ++nt)
          acc[mt][nt] = __builtin_amdgcn_mfma_f32_16x16x32_bf16(af[mt], bfr[nt], acc[mt][nt], 0, 0, 0);
    }
    __syncthreads();
  }
#pragma unroll
  for (int mt = 0; mt < 4; ++mt)
#pragma unroll
    for (int nt = 0; nt < 4; ++nt)
#pragma unroll
      for (int j = 0; j < 4; ++j) {
        int m = bm*128 + wr*64 + mt*16 + lg*4 + j;
        int n = bn*128 + wc*64 + nt*16 + lr;
        float v = acc[mt][nt][j];
        if (BF16OUT) ((u16*)Cp)[(size_t)m * N + n] = f2bf(v);
        else         ((float*)Cp)[(size_t)m * N + n] = v;
      }
}

// ---------------- RoPE + per-head L2 norm (+attn_scale*log2e on Q) ----------------
__global__ __launch_bounds__(256) void rope_norm(const u16* __restrict__ qkv, const float* __restrict__ fc,
                                                 const float* __restrict__ scale_p,
                                                 u16* __restrict__ Qo, u16* __restrict__ Ko) {
  int gid = blockIdx.x;
  int bs = gid >> 2;
  int s = bs & (S_ - 1);
  int b = bs >> 11;
  int w = threadIdx.x >> 6, l = threadIdx.x & 63;
  int h = (gid & 3)*4 + w;
  float2 cs = ((const float2*)fc)[(size_t)s*64 + l];
  // fold log2(e) into Q so flash can use exp2 directly
  float scale = scale_p[0] * 1.4426950408889634f;
  const u16* base = qkv + (size_t)bs * D3_;
  size_t obase = ((size_t)(b*H_ + h) * S_ + s) * HD_ + 2*l;
  // Q
  {
    const u16* p = base + h*HD_ + 2*l;
    float x0 = bf2f(p[0]), x1 = bf2f(p[1]);
    float r0 = x0*cs.x - x1*cs.y;
    float r1 = x1*cs.x + x0*cs.y;
    float t = r0*r0 + r1*r1;
#pragma unroll
    for (int mk = 1; mk < 64; mk <<= 1) t += __shfl_xor(t, mk, 64);
    float inv = scale / (sqrtf(t) + 1e-6f);
    u16x2 o; o[0] = f2bf(r0*inv); o[1] = f2bf(r1*inv);
    *(u16x2*)(Qo + obase) = o;
  }
  // K
  {
    const u16* p = base + D_ + h*HD_ + 2*l;
    float x0 = bf2f(p[0]), x1 = bf2f(p[1]);
    float r0 = x0*cs.x - x1*cs.y;
    float r1 = x1*cs.x + x0*cs.y;
    float t = r0*r0 + r1*r1;
#pragma unroll
    for (int mk = 1; mk < 64; mk <<= 1) t += __shfl_xor(t, mk, 64);
    float inv = 1.0f / (sqrtf(t) + 1e-6f);
    u16x2 o; o[0] = f2bf(r0*inv); o[1] = f2bf(r1*inv);
    *(u16x2*)(Ko + obase) = o;
  }
}

// ---------------- V transpose: qkv v-slice [B,S,H,HD] -> Vt [B*H, HD, S] ----------------
__global__ __launch_bounds__(256) void v_trans(const u16* __restrict__ qkv, u16* __restrict__ Vt) {
  __shared__ u16 vt[64][136];
  int blk = blockIdx.x;
  int bh = blk >> 5, st = blk & 31;
  int b = bh >> 4, h = bh & 15;
  int s0 = st * 64;
  int tid = threadIdx.x;
#pragma unroll
  for (int i = 0; i < 4; ++i) {
    int idx = tid + i*256;
    int row = idx >> 4, ch = idx & 15;
    u16x8 v = *(const u16x8*)(qkv + (size_t)(b*S_ + s0 + row) * D3_ + 2*D_ + h*HD_ + ch*8);
    *(u16x8*)(&vt[row][ch*8]) = v;
  }
  __syncthreads();
#pragma unroll
  for (int p = 0; p < 2; ++p) {
    int d = p*64 + (tid >> 2);
    int q = (tid & 3) * 16;
    u16x8 t0, t1;
#pragma unroll
    for (int i = 0; i < 8; ++i) t0[i] = vt[q + i][d];
#pragma unroll
    for (int i = 0; i < 8; ++i) t1[i] = vt[q + 8 + i][d];
    u16* dst = Vt + ((size_t)bh * HD_ + d) * S_ + s0 + q;
    *(u16x8*)dst = t0;
    *(u16x8*)(dst + 8) = t1;
  }
}

// ---------------- causal flash attention ----------------
// 4 waves, QBLK=64 (16 q-rows/wave), KBLK=64. Double-buffered K/V via
// global_load_lds + counted vmcnt + raw barriers (T3 minimum-2-phase).
// P tile is wave-private LDS (no barrier between write and read).
__global__ __launch_bounds__(256) void flash_attn(const u16* __restrict__ Qh, const u16* __restrict__ Kh,
                                                  const u16* __restrict__ Vt, u16* __restrict__ AO) {
  __shared__ __align__(16) u16 lK[2][64*128];
  __shared__ __align__(16) u16 lV[2][128*64];
  __shared__ __align__(16) u16 lP[4][16*72];
  const int qt = (int)gridDim.x - 1 - (int)blockIdx.x;  // heavy tiles first
  const int bh = blockIdx.y;
  const int tid = threadIdx.x, w = tid >> 6, l = tid & 63;
  const int lr = l & 15, lg = l >> 4;
  const int b = bh >> 4, h = bh & 15;

  bf16x8 qf[4];
  {
    const u16* qp = Qh + ((size_t)bh * S_ + qt*64 + w*16 + lr) * HD_ + lg*8;
#pragma unroll
    for (int ks = 0; ks < 4; ++ks) qf[ks] = *(const bf16x8*)(qp + ks*32);
  }
  float m[4], ls[4];
  f32x4 oacc[8] = {};
#pragma unroll
  for (int j = 0; j < 4; ++j) { m[j] = -__builtin_inff(); ls[j] = 0.f; }

  int ksrow[4], kscol[4], vsrow[4], vscol[4];
#pragma unroll
  for (int i = 0; i < 4; ++i) {
    int off = (w*4 + i)*1024 + l*16;
    ksrow[i] = off >> 8; kscol[i] = (off & 255) ^ ((ksrow[i] & 7) << 4);
    vsrow[i] = off >> 7; vscol[i] = (off & 127) ^ ((vsrow[i] & 7) << 4);
  }
  const char* Kb = (const char*)(Kh + (size_t)bh * S_ * HD_);
  const char* Vb = (const char*)(Vt + (size_t)bh * HD_ * S_);

#define STAGE(nb, kt_) do {                                                        \
    char* lkb_ = (char*)lK[nb]; char* lvb_ = (char*)lV[nb];                        \
    _Pragma("unroll")                                                              \
    for (int i_ = 0; i_ < 4; ++i_) {                                               \
      int dst_ = (w*4 + i_)*1024;                                                  \
      gload_lds16(Kb + (size_t)((kt_)*64 + ksrow[i_])*256 + kscol[i_], lkb_ + dst_); \
      gload_lds16(Vb + (size_t)vsrow[i_]*(S_*2) + (kt_)*128 + vscol[i_], lvb_ + dst_); \
    }                                                                              \
  } while (0)

  STAGE(0, 0);
  int cur = 0;
  for (int kt = 0; kt <= qt; ++kt) {
    if (kt < qt) {
      STAGE(cur ^ 1, kt + 1);                       // prefetch next tile
      asm volatile("s_waitcnt vmcnt(8)" ::: "memory");  // current tile's 8 loads done
    } else {
      asm volatile("s_waitcnt vmcnt(0)" ::: "memory");
    }
    __builtin_amdgcn_s_barrier();
    asm volatile("" ::: "memory");
    const char* lKb = (const char*)lK[cur];
    const char* lVb = (const char*)lV[cur];

    // QK^T
    f32x4 sc[4] = {};
#pragma unroll
    for (int f = 0; f < 4; ++f) {
      int row = f*16 + lr;
#pragma unroll
      for (int ks = 0; ks < 4; ++ks) {
        bf16x8 kf = *(const bf16x8*)(lKb + row*256 + ((ks*64 + lg*16) ^ ((row & 7) << 4)));
        sc[f] = __builtin_amdgcn_mfma_f32_16x16x32_bf16(qf[ks], kf, sc[f], 0, 0, 0);
      }
    }
    if (kt == qt) {
#pragma unroll
      for (int f = 0; f < 4; ++f)
#pragma unroll
        for (int j = 0; j < 4; ++j)
          if (f*16 + lr > w*16 + lg*4 + j) sc[f][j] = -__builtin_inff();
    }
    // online softmax (log2 domain; log2e folded into Q)
    float rm[4], resc[4], rowp[4];
#pragma unroll
    for (int j = 0; j < 4; ++j) {
      rm[j] = fmaxf(fmaxf(sc[0][j], sc[1][j]), fmaxf(sc[2][j], sc[3][j]));
      rm[j] = fmaxf(rm[j], __shfl_xor(rm[j], 1, 64));
      rm[j] = fmaxf(rm[j], __shfl_xor(rm[j], 2, 64));
      rm[j] = fmaxf(rm[j], __shfl_xor(rm[j], 4, 64));
      rm[j] = fmaxf(rm[j], __shfl_xor(rm[j], 8, 64));
      float mn = fmaxf(m[j], rm[j]);
      resc[j] = exp2f(m[j] - mn);
      m[j] = mn;
      rowp[j] = 0.f;
    }
#pragma unroll
    for (int f = 0; f < 4; ++f)
#pragma unroll
      for (int j = 0; j < 4; ++j) {
        float p = exp2f(sc[f][j] - m[j]);
        sc[f][j] = p;
        rowp[j] += p;
      }
#pragma unroll
    for (int j = 0; j < 4; ++j) {
      rowp[j] += __shfl_xor(rowp[j], 1, 64);
      rowp[j] += __shfl_xor(rowp[j], 2, 64);
      rowp[j] += __shfl_xor(rowp[j], 4, 64);
      rowp[j] += __shfl_xor(rowp[j], 8, 64);
      ls[j] = ls[j] * resc[j] + rowp[j];
    }
#pragma unroll
    for (int fd = 0; fd < 8; ++fd)
#pragma unroll
      for (int j = 0; j < 4; ++j) oacc[fd][j] *= resc[j];
    // P -> wave-private LDS (no barrier needed: same-wave DS ops are ordered)
#pragma unroll
    for (int f = 0; f < 4; ++f)
#pragma unroll
      for (int j = 0; j < 4; ++j)
        lP[w][(lg*4 + j)*72 + f*16 + lr] = f2bf(sc[f][j]);
    // PV
#pragma unroll
    for (int ks = 0; ks < 2; ++ks) {
      bf16x8 pf = *(const bf16x8*)((const char*)lP[w] + lr*144 + ks*64 + lg*16);
#pragma unroll
      for (int fd = 0; fd < 8; ++fd) {
        int row = fd*16 + lr;
        bf16x8 vf = *(const bf16x8*)(lVb + row*128 + ((ks*64 + lg*16) ^ ((row & 7) << 4)));
        oacc[fd] = __builtin_amdgcn_mfma_f32_16x16x32_bf16(pf, vf, oacc[fd], 0, 0, 0);
      }
    }
    asm volatile("" ::: "memory");
    __builtin_amdgcn_s_barrier();   // all waves done reading cur before next STAGE overwrites it
    cur ^= 1;
  }
#undef STAGE
  // epilogue
  float invl[4];
#pragma unroll
  for (int j = 0; j < 4; ++j) invl[j] = 1.0f / ls[j];
#pragma unroll
  for (int fd = 0; fd < 8; ++fd)
#pragma unroll
    for (int j = 0; j < 4; ++j) {
      int qq = qt*64 + w*16 + lg*4 + j;
      int dd = fd*16 + lr;
      float v = oacc[fd][j] * invl[j];
      AO[((size_t)b*S_ + qq)*D_ + h*HD_ + dd] = f2bf(v);
    }
}

// ---------------- launch ----------------
extern "C" void kernel_launch(void* const* d_in, const int* in_sizes, int n_in,
                              void* d_out, int out_size, void* d_ws, size_t ws_size,
                              hipStream_t stream) {
  const float* x        = (const float*)d_in[0];
  const float* w_qkv    = (const float*)d_in[1];
  const float* w_out    = (const float*)d_in[2];
  const float* attn_sc  = (const float*)d_in[3];
  const float* freqs    = (const float*)d_in[4];

  if (ws_size < 167772160u) return;  // need 160 MB scratch

  char* ws = (char*)d_ws;
  u16* xbf  = (u16*)(ws);                 //  16 MB  [4096][2048]
  u16* wqbf = (u16*)(ws + 16777216);      //  24 MB  [6144][2048]
  u16* wobf = (u16*)(ws + 41943040);      //   8 MB  [2048][2048]
  u16* qkv  = (u16*)(ws + 50331648);      //  48 MB  [4096][6144]
  u16* Qh   = (u16*)(ws + 100663296);     //  16 MB  [B*H][S][HD]
  u16* Kh   = (u16*)(ws + 117440512);     //  16 MB  [B*H][S][HD]
  u16* Vt   = (u16*)(ws + 134217728);     //  16 MB  [B*H][HD][S]
  u16* AO   = (u16*)(ws + 150994944);     //  16 MB  [4096][2048]

  castk<<<4096, 256, 0, stream>>>(x,     xbf,  8388608);
  castk<<<6144, 256, 0, stream>>>(w_qkv, wqbf, 12582912);
  castk<<<2048, 256, 0, stream>>>(w_out, wobf, 4194304);

  gemm_bt<1><<<dim3(48, 32), 256, 0, stream>>>(xbf, wqbf, qkv, 4096, 6144, 2048);

  rope_norm<<<16384, 256, 0, stream>>>(qkv, freqs, attn_sc, Qh, Kh);
  v_trans<<<1024, 256, 0, stream>>>(qkv, Vt);

  flash_attn<<<dim3(32, 32), 256, 0, stream>>>(Qh, Kh, Vt, AO);

  gemm_bt<0><<<dim3(16, 32), 256, 0, stream>>>(AO, wobf, (float*)d_out, 4096, 2048, 2048);
}

// Round 3
// 328.726 us; speedup vs baseline: 1.1873x; 1.1873x over previous
//
#include <hip/hip_runtime.h>
#include <stdint.h>

#define B_  2
#define S_  2048
#define D_  2048
#define H_  16
#define HD_ 128
#define D3_ 6144

typedef unsigned short u16;
typedef __attribute__((ext_vector_type(8))) __bf16 bf16x8;
typedef __attribute__((ext_vector_type(4))) float f32x4;
typedef __attribute__((ext_vector_type(8))) u16  u16x8;
typedef __attribute__((ext_vector_type(2))) u16  u16x2;

__device__ inline u16 f2bf(float f) {
  union { float f; uint32_t u; } v; v.f = f;
  uint32_t r = v.u + 0x7FFFu + ((v.u >> 16) & 1u);
  return (u16)(r >> 16);
}
__device__ inline float bf2f(u16 u) {
  union { float f; uint32_t u; } v; v.u = ((uint32_t)u) << 16;
  return v.f;
}
__device__ inline void gload_lds16(const void* g, void* l) {
  __builtin_amdgcn_global_load_lds((const __attribute__((address_space(1))) uint32_t*)g,
                                   (__attribute__((address_space(3))) uint32_t*)l, 16, 0, 0);
}

// ---------------- fp32 -> bf16 cast ----------------
__global__ __launch_bounds__(256) void castk(const float* __restrict__ in, u16* __restrict__ out, int n) {
  int i = blockIdx.x * 256 + threadIdx.x;
  int n8 = n >> 3;
  if (i < n8) {
    f32x4 a = ((const f32x4*)in)[2*i];
    f32x4 b = ((const f32x4*)in)[2*i + 1];
    u16x8 o;
#pragma unroll
    for (int j = 0; j < 4; ++j) o[j] = f2bf(a[j]);
#pragma unroll
    for (int j = 0; j < 4; ++j) o[4+j] = f2bf(b[j]);
    ((u16x8*)out)[i] = o;
  }
}

// ---------------- B^T GEMM: C[m,n] = sum_k A[m,k]*B[n,k] ----------------
// 128x128 tile, BK=64, 4 waves. XCD-aware block swizzle (T1).
template<int BF16OUT>
__global__ __launch_bounds__(256) void gemm_bt(const u16* __restrict__ A, const u16* __restrict__ Bw,
                                               void* __restrict__ Cp, int M, int N, int K) {
  __shared__ u16 lA[128*64];
  __shared__ u16 lB[128*64];
  const int tid = threadIdx.x;
  const int w = tid >> 6, l = tid & 63;
  const int lr = l & 15, lg = l >> 4;
  // XCD swizzle: nwg % 8 == 0 for all our shapes
  const int nwg = (int)(gridDim.x * gridDim.y);
  const int bid = (int)(blockIdx.y * gridDim.x + blockIdx.x);
  const int swz = (bid & 7) * (nwg >> 3) + (bid >> 3);
  const int bm = swz / (int)gridDim.x, bn = swz % (int)gridDim.x;
  const int wr = w >> 1, wc = w & 1;

  f32x4 acc[4][4] = {};

  int srow[4], scol[4];
#pragma unroll
  for (int i = 0; i < 4; ++i) {
    int off = (w*4 + i)*1024 + l*16;
    srow[i] = off >> 7;
    scol[i] = (off & 127) ^ ((srow[i] & 7) << 4);
  }
  const size_t rs = (size_t)K * 2;
  const char* Ab = (const char*)A + (size_t)bm * 128 * rs;
  const char* Bb = (const char*)Bw + (size_t)bn * 128 * rs;
  char* lAb = (char*)lA; char* lBb = (char*)lB;

  for (int kt = 0; kt < K; kt += 64) {
#pragma unroll
    for (int i = 0; i < 4; ++i) {
      int dst = (w*4 + i)*1024;
      gload_lds16(Ab + srow[i]*rs + kt*2 + scol[i], lAb + dst);
      gload_lds16(Bb + srow[i]*rs + kt*2 + scol[i], lBb + dst);
    }
    __syncthreads();
#pragma unroll
    for (int ks = 0; ks < 2; ++ks) {
      bf16x8 af[4], bfr[4];
#pragma unroll
      for (int mt = 0; mt < 4; ++mt) {
        int row = wr*64 + mt*16 + lr;
        af[mt] = *(const bf16x8*)(lAb + row*128 + ((ks*64 + lg*16) ^ ((row & 7) << 4)));
      }
#pragma unroll
      for (int nt = 0; nt < 4; ++nt) {
        int row = wc*64 + nt*16 + lr;
        bfr[nt] = *(const bf16x8*)(lBb + row*128 + ((ks*64 + lg*16) ^ ((row & 7) << 4)));
      }
#pragma unroll
      for (int mt = 0; mt < 4; ++mt)
#pragma unroll
        for (int nt = 0; nt < 4; ++nt)
          acc[mt][nt] = __builtin_amdgcn_mfma_f32_16x16x32_bf16(af[mt], bfr[nt], acc[mt][nt], 0, 0, 0);
    }
    __syncthreads();
  }
#pragma unroll
  for (int mt = 0; mt < 4; ++mt)
#pragma unroll
    for (int nt = 0; nt < 4; ++nt)
#pragma unroll
      for (int j = 0; j < 4; ++j) {
        int m = bm*128 + wr*64 + mt*16 + lg*4 + j;
        int n = bn*128 + wc*64 + nt*16 + lr;
        float v = acc[mt][nt][j];
        if (BF16OUT) ((u16*)Cp)[(size_t)m * N + n] = f2bf(v);
        else         ((float*)Cp)[(size_t)m * N + n] = v;
      }
}

// ---------------- RoPE + per-head L2 norm (+attn_scale*log2e on Q) ----------------
__global__ __launch_bounds__(256) void rope_norm(const u16* __restrict__ qkv, const float* __restrict__ fc,
                                                 const float* __restrict__ scale_p,
                                                 u16* __restrict__ Qo, u16* __restrict__ Ko) {
  int gid = blockIdx.x;
  int bs = gid >> 2;
  int s = bs & (S_ - 1);
  int b = bs >> 11;
  int w = threadIdx.x >> 6, l = threadIdx.x & 63;
  int h = (gid & 3)*4 + w;
  float2 cs = ((const float2*)fc)[(size_t)s*64 + l];
  float scale = scale_p[0] * 1.4426950408889634f;  // fold log2(e) for exp2 softmax
  const u16* base = qkv + (size_t)bs * D3_;
  size_t obase = ((size_t)(b*H_ + h) * S_ + s) * HD_ + 2*l;
  {
    const u16* p = base + h*HD_ + 2*l;
    float x0 = bf2f(p[0]), x1 = bf2f(p[1]);
    float r0 = x0*cs.x - x1*cs.y;
    float r1 = x1*cs.x + x0*cs.y;
    float t = r0*r0 + r1*r1;
#pragma unroll
    for (int mk = 1; mk < 64; mk <<= 1) t += __shfl_xor(t, mk, 64);
    float inv = scale / (sqrtf(t) + 1e-6f);
    u16x2 o; o[0] = f2bf(r0*inv); o[1] = f2bf(r1*inv);
    *(u16x2*)(Qo + obase) = o;
  }
  {
    const u16* p = base + D_ + h*HD_ + 2*l;
    float x0 = bf2f(p[0]), x1 = bf2f(p[1]);
    float r0 = x0*cs.x - x1*cs.y;
    float r1 = x1*cs.x + x0*cs.y;
    float t = r0*r0 + r1*r1;
#pragma unroll
    for (int mk = 1; mk < 64; mk <<= 1) t += __shfl_xor(t, mk, 64);
    float inv = 1.0f / (sqrtf(t) + 1e-6f);
    u16x2 o; o[0] = f2bf(r0*inv); o[1] = f2bf(r1*inv);
    *(u16x2*)(Ko + obase) = o;
  }
}

// ---------------- V transpose: qkv v-slice [B,S,H,HD] -> Vt [B*H, HD, S] ----------------
__global__ __launch_bounds__(256) void v_trans(const u16* __restrict__ qkv, u16* __restrict__ Vt) {
  __shared__ u16 vt[64][136];
  int blk = blockIdx.x;
  int bh = blk >> 5, st = blk & 31;
  int b = bh >> 4, h = bh & 15;
  int s0 = st * 64;
  int tid = threadIdx.x;
#pragma unroll
  for (int i = 0; i < 4; ++i) {
    int idx = tid + i*256;
    int row = idx >> 4, ch = idx & 15;
    u16x8 v = *(const u16x8*)(qkv + (size_t)(b*S_ + s0 + row) * D3_ + 2*D_ + h*HD_ + ch*8);
    *(u16x8*)(&vt[row][ch*8]) = v;
  }
  __syncthreads();
#pragma unroll
  for (int p = 0; p < 2; ++p) {
    int d = p*64 + (tid >> 2);
    int q = (tid & 3) * 16;
    u16x8 t0, t1;
#pragma unroll
    for (int i = 0; i < 8; ++i) t0[i] = vt[q + i][d];
#pragma unroll
    for (int i = 0; i < 8; ++i) t1[i] = vt[q + 8 + i][d];
    u16* dst = Vt + ((size_t)bh * HD_ + d) * S_ + s0 + q;
    *(u16x8*)dst = t0;
    *(u16x8*)(dst + 8) = t1;
  }
}

// ---------------- causal flash attention ----------------
// QBLK=128, 8 waves (512 thr), KBLK=64. K double-buffered, V single-buffered
// (latency hides under QK^T+softmax). Counted vmcnt, never 0 except last tile.
// Balanced block mapping: q-tile t paired with 15-t so per-CU work is uniform.
__global__ __launch_bounds__(512) void flash_attn(const u16* __restrict__ Qh, const u16* __restrict__ Kh,
                                                  const u16* __restrict__ Vt, u16* __restrict__ AO) {
  __shared__ __align__(16) u16 lK[2][64*128];   // 32 KB
  __shared__ __align__(16) u16 lV[128*64];      // 16 KB
  __shared__ __align__(16) u16 lP[8][16*72];    // 18 KB
  const int i0 = (int)blockIdx.x;               // 0..511
  const int k5 = i0 & 255;
  const int bh = k5 >> 3;
  const int jj = k5 & 7;
  const int qt = (i0 < 256) ? (15 - jj) : jj;   // heavy half first
  const int tid = threadIdx.x, w = tid >> 6, l = tid & 63;
  const int lr = l & 15, lg = l >> 4;
  const int b = bh >> 4, h = bh & 15;

  bf16x8 qf[4];
  {
    const u16* qp = Qh + ((size_t)bh * S_ + qt*128 + w*16 + lr) * HD_ + lg*8;
#pragma unroll
    for (int ks = 0; ks < 4; ++ks) qf[ks] = *(const bf16x8*)(qp + ks*32);
  }
  float m[4], ls[4];
  f32x4 oacc[8] = {};
#pragma unroll
  for (int j = 0; j < 4; ++j) { m[j] = -__builtin_inff(); ls[j] = 0.f; }

  // staging: 512 threads x 16B x 2 passes = 16KB tile
  int krow[2], kcol[2], vrow[2], vcol[2], dstb[2];
#pragma unroll
  for (int p = 0; p < 2; ++p) {
    int off = p*8192 + tid*16;
    krow[p] = off >> 8; kcol[p] = (off & 255) ^ ((krow[p] & 7) << 4);
    vrow[p] = off >> 7; vcol[p] = (off & 127) ^ ((vrow[p] & 7) << 4);
    dstb[p] = p*8192 + w*1024;   // wave-uniform LDS dest base (HW adds lane*16)
  }
  const char* Kb = (const char*)(Kh + (size_t)bh * S_ * HD_);
  const char* Vb = (const char*)(Vt + (size_t)bh * HD_ * S_);

#define STAGE_K(nb, kt_) do {                                                       \
    _Pragma("unroll")                                                               \
    for (int p_ = 0; p_ < 2; ++p_)                                                  \
      gload_lds16(Kb + (size_t)((kt_)*64 + krow[p_])*256 + kcol[p_],                \
                  (char*)lK[nb] + dstb[p_]);                                        \
  } while (0)
#define STAGE_V(kt_) do {                                                           \
    _Pragma("unroll")                                                               \
    for (int p_ = 0; p_ < 2; ++p_)                                                  \
      gload_lds16(Vb + (size_t)vrow[p_]*(S_*2) + (kt_)*128 + vcol[p_],              \
                  (char*)lV + dstb[p_]);                                            \
  } while (0)

  const int nt = 2*qt + 2;
  STAGE_K(0, 0);
  STAGE_V(0);
  int cur = 0;
  for (int kt = 0; kt < nt; ++kt) {
    // K[cur] ready (own 2 K loads are the oldest; <=2 outstanding leaves newer V/K)
    asm volatile("s_waitcnt vmcnt(2)" ::: "memory");
    __builtin_amdgcn_s_barrier();
    asm volatile("" ::: "memory");
    const char* lKb = (const char*)lK[cur];

    // QK^T
    f32x4 sc[4] = {};
#pragma unroll
    for (int f = 0; f < 4; ++f) {
      int row = f*16 + lr;
#pragma unroll
      for (int ks = 0; ks < 4; ++ks) {
        bf16x8 kf = *(const bf16x8*)(lKb + row*256 + ((ks*64 + lg*16) ^ ((row & 7) << 4)));
        sc[f] = __builtin_amdgcn_mfma_f32_16x16x32_bf16(qf[ks], kf, sc[f], 0, 0, 0);
      }
    }
    if (kt < nt-1) STAGE_K(cur ^ 1, kt + 1);   // prefetch next K under softmax

    if (kt >= nt-2) {  // diagonal tiles only
#pragma unroll
      for (int f = 0; f < 4; ++f)
#pragma unroll
        for (int j = 0; j < 4; ++j)
          if (kt*64 + f*16 + lr > qt*128 + w*16 + lg*4 + j) sc[f][j] = -__builtin_inff();
    }
    // online softmax (base-2; log2e folded into Q)
    float rm[4], resc[4], rowp[4];
#pragma unroll
    for (int j = 0; j < 4; ++j) {
      rm[j] = fmaxf(fmaxf(sc[0][j], sc[1][j]), fmaxf(sc[2][j], sc[3][j]));
      rm[j] = fmaxf(rm[j], __shfl_xor(rm[j], 1, 64));
      rm[j] = fmaxf(rm[j], __shfl_xor(rm[j], 2, 64));
      rm[j] = fmaxf(rm[j], __shfl_xor(rm[j], 4, 64));
      rm[j] = fmaxf(rm[j], __shfl_xor(rm[j], 8, 64));
      float mn = fmaxf(m[j], rm[j]);
      resc[j] = exp2f(m[j] - mn);
      m[j] = mn;
      rowp[j] = 0.f;
    }
#pragma unroll
    for (int f = 0; f < 4; ++f)
#pragma unroll
      for (int j = 0; j < 4; ++j) {
        float p = exp2f(sc[f][j] - m[j]);
        sc[f][j] = p;
        rowp[j] += p;
      }
#pragma unroll
    for (int j = 0; j < 4; ++j) {
      rowp[j] += __shfl_xor(rowp[j], 1, 64);
      rowp[j] += __shfl_xor(rowp[j], 2, 64);
      rowp[j] += __shfl_xor(rowp[j], 4, 64);
      rowp[j] += __shfl_xor(rowp[j], 8, 64);
      ls[j] = ls[j] * resc[j] + rowp[j];
    }
#pragma unroll
    for (int fd = 0; fd < 8; ++fd)
#pragma unroll
      for (int j = 0; j < 4; ++j) oacc[fd][j] *= resc[j];
    // P -> wave-private LDS
#pragma unroll
    for (int f = 0; f < 4; ++f)
#pragma unroll
      for (int j = 0; j < 4; ++j)
        lP[w][(lg*4 + j)*72 + f*16 + lr] = f2bf(sc[f][j]);

    // V ready: its 2 loads are oldest among outstanding (V cur, then K next)
    if (kt < nt-1) { asm volatile("s_waitcnt vmcnt(2)" ::: "memory"); }
    else           { asm volatile("s_waitcnt vmcnt(0)" ::: "memory"); }
    __builtin_amdgcn_s_barrier();
    asm volatile("" ::: "memory");
    // PV
#pragma unroll
    for (int ks = 0; ks < 2; ++ks) {
      bf16x8 pf = *(const bf16x8*)((const char*)lP[w] + lr*144 + ks*64 + lg*16);
#pragma unroll
      for (int fd = 0; fd < 8; ++fd) {
        int row = fd*16 + lr;
        bf16x8 vf = *(const bf16x8*)((const char*)lV + row*128 + ((ks*64 + lg*16) ^ ((row & 7) << 4)));
        oacc[fd] = __builtin_amdgcn_mfma_f32_16x16x32_bf16(pf, vf, oacc[fd], 0, 0, 0);
      }
    }
    asm volatile("" ::: "memory");
    __builtin_amdgcn_s_barrier();   // all waves done with lV (and lK[cur]) before overwrite
    asm volatile("" ::: "memory");
    if (kt < nt-1) STAGE_V(kt + 1);
    cur ^= 1;
  }
#undef STAGE_K
#undef STAGE_V
  // epilogue
  float invl[4];
#pragma unroll
  for (int j = 0; j < 4; ++j) invl[j] = 1.0f / ls[j];
#pragma unroll
  for (int fd = 0; fd < 8; ++fd)
#pragma unroll
    for (int j = 0; j < 4; ++j) {
      int qq = qt*128 + w*16 + lg*4 + j;
      int dd = fd*16 + lr;
      float v = oacc[fd][j] * invl[j];
      AO[((size_t)b*S_ + qq)*D_ + h*HD_ + dd] = f2bf(v);
    }
}

// ---------------- launch ----------------
extern "C" void kernel_launch(void* const* d_in, const int* in_sizes, int n_in,
                              void* d_out, int out_size, void* d_ws, size_t ws_size,
                              hipStream_t stream) {
  const float* x        = (const float*)d_in[0];
  const float* w_qkv    = (const float*)d_in[1];
  const float* w_out    = (const float*)d_in[2];
  const float* attn_sc  = (const float*)d_in[3];
  const float* freqs    = (const float*)d_in[4];

  if (ws_size < 167772160u) return;  // need 160 MB scratch

  char* ws = (char*)d_ws;
  u16* xbf  = (u16*)(ws);                 //  16 MB  [4096][2048]
  u16* wqbf = (u16*)(ws + 16777216);      //  24 MB  [6144][2048]
  u16* wobf = (u16*)(ws + 41943040);      //   8 MB  [2048][2048]
  u16* qkv  = (u16*)(ws + 50331648);      //  48 MB  [4096][6144]
  u16* Qh   = (u16*)(ws + 100663296);     //  16 MB  [B*H][S][HD]
  u16* Kh   = (u16*)(ws + 117440512);     //  16 MB  [B*H][S][HD]
  u16* Vt   = (u16*)(ws + 134217728);     //  16 MB  [B*H][HD][S]
  u16* AO   = (u16*)(ws + 150994944);     //  16 MB  [4096][2048]

  castk<<<4096, 256, 0, stream>>>(x,     xbf,  8388608);
  castk<<<6144, 256, 0, stream>>>(w_qkv, wqbf, 12582912);
  castk<<<2048, 256, 0, stream>>>(w_out, wobf, 4194304);

  gemm_bt<1><<<dim3(48, 32), 256, 0, stream>>>(xbf, wqbf, qkv, 4096, 6144, 2048);

  rope_norm<<<16384, 256, 0, stream>>>(qkv, freqs, attn_sc, Qh, Kh);
  v_trans<<<1024, 256, 0, stream>>>(qkv, Vt);

  flash_attn<<<512, 512, 0, stream>>>(Qh, Kh, Vt, AO);

  gemm_bt<0><<<dim3(16, 32), 256, 0, stream>>>(AO, wobf, (float*)d_out, 4096, 2048, 2048);
}